// Round 8
// baseline (1066.464 us; speedup 1.0000x reference)
//
#include <hip/hip_runtime.h>

// ---------- types ----------
typedef __attribute__((ext_vector_type(8))) short short8;
typedef __attribute__((ext_vector_type(8))) unsigned short ushort8;
typedef __attribute__((ext_vector_type(4))) float f32x4;

__device__ __forceinline__ float b2f(short s) {
    unsigned u = ((unsigned)(unsigned short)s) << 16;
    return __builtin_bit_cast(float, u);
}
__device__ __forceinline__ unsigned short f2b(float f) {
    unsigned u = __builtin_bit_cast(unsigned, f);
    u += 0x7fffu + ((u >> 16) & 1u);   // round-to-nearest-even
    return (unsigned short)(u >> 16);
}

// global -> LDS async copy, 16B per lane (wave-uniform LDS base + lane*16)
__device__ __forceinline__ void gload_lds16(const void* gptr, void* ldsptr) {
    typedef __attribute__((address_space(1))) const void gv_t;
    typedef __attribute__((address_space(3))) void lv_t;
    gv_t* g = reinterpret_cast<gv_t*>(reinterpret_cast<unsigned long long>(gptr));
    lv_t* l = reinterpret_cast<lv_t*>((unsigned int)reinterpret_cast<unsigned long long>(ldsptr));
    __builtin_amdgcn_global_load_lds(g, l, 16, 0, 0);
}

#define MEMFENCE() asm volatile("" ::: "memory")
#define BARRIER() do { MEMFENCE(); __builtin_amdgcn_s_barrier(); MEMFENCE(); } while (0)

// ---------- one-shot fp32->bf16 conversion for all inputs + bias concat ----------
__global__ __launch_bounds__(256) void cvt_all(const float* __restrict__ x,
                                               const float* __restrict__ Wq,
                                               const float* __restrict__ Wk,
                                               const float* __restrict__ Wv,
                                               const float* __restrict__ Wo,
                                               const float* __restrict__ bq,
                                               const float* __restrict__ bk,
                                               const float* __restrict__ bv,
                                               unsigned short* __restrict__ xb,
                                               unsigned short* __restrict__ wqkv,
                                               unsigned short* __restrict__ wo,
                                               float* __restrict__ bqkv) {
    const int bid = blockIdx.x;
    const float* src;
    unsigned short* dst;
    int base8;
    if (bid < 16384)      { src = x;  dst = xb;              base8 = bid; }
    else if (bid < 16896) { src = Wq; dst = wqkv;            base8 = bid - 16384; }
    else if (bid < 17408) { src = Wk; dst = wqkv + 1048576;  base8 = bid - 16896; }
    else if (bid < 17920) { src = Wv; dst = wqkv + 2097152;  base8 = bid - 17408; }
    else if (bid < 18432) { src = Wo; dst = wo;              base8 = bid - 17920; }
    else {
        const int i = threadIdx.x;
#pragma unroll
        for (int r = 0; r < 12; ++r) {   // 3072 floats
            int j = r * 256 + i;
            float v = (j < 1024) ? bq[j] : (j < 2048 ? bk[j - 1024] : bv[j - 2048]);
            bqkv[j] = v;
        }
        return;
    }
    const size_t i8 = (size_t)base8 * 256 + threadIdx.x;
    const float4* p = (const float4*)src + i8 * 2;
    float4 a = p[0], b = p[1];
    ushort8 o;
    o[0] = f2b(a.x); o[1] = f2b(a.y); o[2] = f2b(a.z); o[3] = f2b(a.w);
    o[4] = f2b(b.x); o[5] = f2b(b.y); o[6] = f2b(b.z); o[7] = f2b(b.w);
    *(ushort8*)(dst + i8 * 8) = o;
}

// ---------- GEMM-DP (experimental, G1): 256x256, BK=64, 4 waves, 1 wave/SIMD ----------
// Per-wave output 128x128 (acc 256 VGPR; full 512-VGPR budget at 1 wave/EU).
// Per tile per wave: 32 ds_read_b128 (LDS pipe ~1024 cyc/CU) vs 128 MFMA
// (~2060 cyc/SIMD) -> LDS latency fully hideable under MFMA. Schedule:
//   [ks1 reads issue | lgkm(15) | 64 MFMA ks0 (ks1 drains under) | lgkm(0) |
//    barrier | stage(t+2,d) | vmcnt(16) (t+1 landed, t+2 in flight) | barrier |
//    ks0' reads of t+1 | 64 MFMA ks1 (ks0' reads drain under)]
// 2 barriers/tile. (lgkmcnt max is 15 on gfx9 — 15 means "16 ks0 + 1 ks1
// serviced" out of 32 outstanding; one read stronger than needed, safe.)
// Hazards: all waves pass lgkm(0) before the barrier that precedes re-staging
// buf d; vmcnt(16)+barrier publishes t+1 before its reads. sched_barrier(0) x2
// pins the MFMA blobs against rule-#18 hoisting. Swizzle = R4's 0-conflict
// math (8 granules/row, phys ^= row&7; linear gload dest + pre-swz source).
template <bool OUT_BF16>
__global__ __launch_bounds__(256, 1) void gemm_dp(const short* __restrict__ A,   // [M,K]
                                                  const short* __restrict__ B,   // [N,K]
                                                  const float* __restrict__ bias,
                                                  unsigned short* __restrict__ Cb,
                                                  float* __restrict__ Cf,
                                                  int M, int N, int K) {
    extern __shared__ short lds[];    // A[2][256][64] | B[2][256][64] = 128 KiB
    short* Ab = lds;
    short* Bb = lds + 32768;

    const int lane = threadIdx.x & 63;
    const int wave = threadIdx.x >> 6;   // 0..3
    const int wr = wave >> 1, wc = wave & 1;

    const int nwg = gridDim.x;
    const int bid = blockIdx.x;
    const int swz = (bid & 7) * (nwg >> 3) + (bid >> 3);
    const int ncol = N >> 8;
    const int trow = swz / ncol, tcol = swz % ncol;

    const short* Ablk = A + (size_t)trow * 256 * K;
    const short* Bblk = B + (size_t)tcol * 256 * K;

    const int srow_off = lane >> 3;                      // 0..7 within 8-row stripe
    const int scol_sw = ((lane & 7) ^ (lane >> 3)) * 8;  // pre-swizzled source granule
    const int rl = lane & 15;
    const int g0 = ((lane >> 4) ^ (lane & 7)) * 8;       // ks0 phys granule (shorts)
    const int g1 = ((4 + (lane >> 4)) ^ (lane & 7)) * 8; // ks1 phys granule

    short8 a0[8], a1[8], b0[8], b1[8];
    f32x4 acc[8][8] = {};

    const int NT = K >> 6;

    auto stage = [&](int t, int d) {
#pragma unroll
        for (int i = 0; i < 8; ++i) {
            const int stripe = i * 4 + wave;             // 0..31 (wave-uniform)
            gload_lds16(Ablk + (size_t)(stripe * 8 + srow_off) * K + t * 64 + scol_sw,
                        Ab + d * 16384 + stripe * 512);
            gload_lds16(Bblk + (size_t)(stripe * 8 + srow_off) * K + t * 64 + scol_sw,
                        Bb + d * 16384 + stripe * 512);
        }
    };
    auto readA = [&](int d, int g, short8* dst) {
        const short* base = Ab + d * 16384 + (wr * 128 + rl) * 64 + g;
#pragma unroll
        for (int m = 0; m < 8; ++m) dst[m] = *(const short8*)(base + m * 16 * 64);
    };
    auto readB = [&](int d, int g, short8* dst) {
        const short* base = Bb + d * 16384 + (wc * 128 + rl) * 64 + g;
#pragma unroll
        for (int n = 0; n < 8; ++n) dst[n] = *(const short8*)(base + n * 16 * 64);
    };
    auto mmhalf = [&](short8* av, short8* bv) {
        __builtin_amdgcn_s_setprio(1);
#pragma unroll
        for (int m = 0; m < 8; ++m)
#pragma unroll
            for (int n = 0; n < 8; ++n)
                acc[m][n] = __builtin_amdgcn_mfma_f32_16x16x32_bf16(av[m], bv[n], acc[m][n], 0, 0, 0);
        __builtin_amdgcn_s_setprio(0);
    };

    // prologue: stage tiles 0,1; tile0 landed (tile1 in flight); read ks0 of tile0
    stage(0, 0);
    stage(1, 1);
    asm volatile("s_waitcnt vmcnt(16)" ::: "memory");
    BARRIER();
    readA(0, g0, a0); readB(0, g0, b0);

    for (int t = 0; t < NT; ++t) {
        const int d = t & 1;
        // ks1 reads issue, then MFMA ks0 runs while they drain
        readA(d, g1, a1); readB(d, g1, b1);
        asm volatile("s_waitcnt lgkmcnt(15)" ::: "memory");   // ks0 frags serviced (max field = 15)
        mmhalf(a0, b0);
        __builtin_amdgcn_sched_barrier(0);                     // pin mm before sync section
        asm volatile("s_waitcnt lgkmcnt(0)" ::: "memory");     // ks1 frags serviced (all reads of buf d done)
        BARRIER();                                             // all waves done reading buf d
        if (t + 2 < NT) stage(t + 2, d);
        if (t + 1 < NT) {
            if (t + 2 < NT) asm volatile("s_waitcnt vmcnt(16)" ::: "memory");  // t+1 landed
            else            asm volatile("s_waitcnt vmcnt(0)"  ::: "memory");
        }
        BARRIER();                                             // tile t+1 visible
        if (t + 1 < NT) { readA(d ^ 1, g0, a0); readB(d ^ 1, g0, b0); }
        __builtin_amdgcn_sched_barrier(0);                     // reads issue before mm
        mmhalf(a1, b1);                                        // ks0' reads drain under this
    }

    // epilogue: C/D layout col = lane&15, row = (lane>>4)*4 + r
    const int crow0 = trow * 256 + wr * 128 + (lane >> 4) * 4;
    const int ccol0 = tcol * 256 + wc * 128 + rl;
#pragma unroll
    for (int n = 0; n < 8; ++n) {
        const int col = ccol0 + n * 16;
        const float bv = bias[col];
#pragma unroll
        for (int m = 0; m < 8; ++m) {
            const int row0 = crow0 + m * 16;
#pragma unroll
            for (int r = 0; r < 4; ++r) {
                float val = acc[m][n][r] + bv;
                if (OUT_BF16) Cb[(size_t)(row0 + r) * N + col] = f2b(val);
                else          Cf[(size_t)(row0 + r) * N + col] = val;
            }
        }
    }
}

// ---------- GEMM (R4-proven control, G2): 256x256, BK=64, 8 waves, 4-phase ----------
template <bool OUT_BF16>
__global__ __launch_bounds__(512, 2) void gemm_bt(const short* __restrict__ A,
                                                  const short* __restrict__ B,
                                                  const float* __restrict__ bias,
                                                  unsigned short* __restrict__ Cb,
                                                  float* __restrict__ Cf,
                                                  int M, int N, int K) {
    extern __shared__ short lds[];
    short* Ab = lds;                       // [2][2][128][64]
    short* Bb = lds + 2 * 2 * 128 * 64;    // [2][2][128][64]

    const int lane = threadIdx.x & 63;
    const int wave = threadIdx.x >> 6;
    const int wr = wave >> 2;
    const int wc = wave & 3;

    const int nwg = gridDim.x;
    const int bid = blockIdx.x;
    const int swz = (bid & 7) * (nwg >> 3) + (bid >> 3);
    const int ncol = N >> 8;
    const int trow = swz / ncol, tcol = swz % ncol;

    const short* Ablk = A + (size_t)trow * 256 * K;
    const short* Bblk = B + (size_t)tcol * 256 * K;

    const int scol_sw = ((lane & 7) ^ (lane >> 3)) * 8;
    const int rl = lane & 15;
    const int g0 = (((lane >> 4)) ^ (lane & 7)) * 8;
    const int g1 = ((4 + (lane >> 4)) ^ (lane & 7)) * 8;

    short8 af[4][2];
    short8 bf[4][2];
    f32x4 acc[8][4] = {};

    const int NT = K >> 6;
    const int smax = 4 * (NT - 2);

    auto stage_half = [&](int ts, int h) {
        const int dd = ts & 1;
        const int hh = h & 1;
        const short* gb = ((h < 2) ? Ablk : Bblk) + (size_t)(hh * 128) * K + (ts << 6) + scol_sw;
        short* lb = ((h < 2) ? Ab : Bb) + (((dd << 1) | hh) << 13);
#pragma unroll
        for (int c = 0; c < 2; ++c) {
            const int row = c * 64 + wave * 8 + (lane >> 3);
            gload_lds16(gb + (size_t)row * K, lb + ((c * 64 + wave * 8) << 6));
        }
    };
    auto stage_if = [&](int s) { if (s >= 0 && s < smax) stage_half((s >> 2) + 2, s & 3); };

    auto readA = [&](int d, int mh) {
        const short* base = Ab + (((d << 1) | wr) << 13) + ((mh * 64 + rl) << 6);
#pragma unroll
        for (int m = 0; m < 4; ++m) {
            af[m][0] = *(const short8*)(base + ((m * 16) << 6) + g0);
            af[m][1] = *(const short8*)(base + ((m * 16) << 6) + g1);
        }
    };
    auto readB = [&](int d, int nh) {
        const short* base = Bb + (((d << 1) | (wc >> 1)) << 13) + (((wc & 1) * 64 + rl) << 6);
#pragma unroll
        for (int j = 0; j < 2; ++j) {
            bf[nh * 2 + j][0] = *(const short8*)(base + (((nh * 2 + j) * 16) << 6) + g0);
            bf[nh * 2 + j][1] = *(const short8*)(base + (((nh * 2 + j) * 16) << 6) + g1);
        }
    };
    auto mm = [&](int mh, int nh) {
        __builtin_amdgcn_s_setprio(1);
#pragma unroll
        for (int ks = 0; ks < 2; ++ks)
#pragma unroll
            for (int m = 0; m < 4; ++m)
#pragma unroll
                for (int j = 0; j < 2; ++j)
                    acc[mh * 4 + m][nh * 2 + j] = __builtin_amdgcn_mfma_f32_16x16x32_bf16(
                        af[m][ks], bf[nh * 2 + j][ks], acc[mh * 4 + m][nh * 2 + j], 0, 0, 0);
        __builtin_amdgcn_s_setprio(0);
    };

    auto tile_body = [&](int T, int d) {
        const int s0 = 4 * T;
        readA(d, 0); readB(d, 0);
        stage_if(s0 - 3);
        asm volatile("s_waitcnt lgkmcnt(8)" ::: "memory");
        BARRIER();
        asm volatile("s_waitcnt lgkmcnt(0)" ::: "memory");
        mm(0, 0);
        BARRIER();
        readB(d, 1);
        stage_if(s0 - 2);
        BARRIER();
        asm volatile("s_waitcnt lgkmcnt(0)" ::: "memory");
        mm(0, 1);
        BARRIER();
        readA(d, 1);
        stage_if(s0 - 1);
        BARRIER();
        asm volatile("s_waitcnt lgkmcnt(0)" ::: "memory");
        mm(1, 0);
        BARRIER();
        stage_if(s0);
        BARRIER();
        mm(1, 1);
        if (T < NT - 2)       asm volatile("s_waitcnt vmcnt(2)" ::: "memory");
        else if (T == NT - 2) asm volatile("s_waitcnt vmcnt(0)" ::: "memory");
        BARRIER();
    };

#pragma unroll
    for (int t = 0; t < 2; ++t)
#pragma unroll
        for (int h = 0; h < 4; ++h) stage_half(t, h);
    asm volatile("s_waitcnt vmcnt(8)" ::: "memory");
    BARRIER();

    for (int T2 = 0; T2 < NT; T2 += 2) {
        tile_body(T2, 0);
        tile_body(T2 + 1, 1);
    }

    const int crow0 = trow * 256 + wr * 128 + (lane >> 4) * 4;
    const int ccol0 = tcol * 256 + wc * 64 + rl;
#pragma unroll
    for (int n = 0; n < 4; ++n) {
        const int col = ccol0 + n * 16;
        const float bv = bias[col];
#pragma unroll
        for (int m = 0; m < 8; ++m) {
            const int row0 = crow0 + m * 16;
#pragma unroll
            for (int r = 0; r < 4; ++r) {
                float val = acc[m][n][r] + bv;
                if (OUT_BF16) Cb[(size_t)(row0 + r) * N + col] = f2b(val);
                else          Cf[(size_t)(row0 + r) * N + col] = val;
            }
        }
    }
}

// ---------- per-token cross-head attention ----------
__global__ __launch_bounds__(256) void attn_k(const short* __restrict__ qkv,
                                              short* __restrict__ out) {
    int gid = blockIdx.x * 256 + threadIdx.x;
    int t = gid >> 4, h = gid & 15;
    const short* q  = qkv + (size_t)t * 3072 + h * 64;
    const short* kb = qkv + (size_t)t * 3072 + 1024;
    const short* vb = qkv + (size_t)t * 3072 + 2048;

    float qf[64];
#pragma unroll
    for (int j = 0; j < 8; ++j) {
        short8 qv = *(const short8*)(q + j * 8);
#pragma unroll
        for (int i = 0; i < 8; ++i) qf[j * 8 + i] = b2f(qv[i]);
    }

    float s[16];
    float mx = -1e30f;
#pragma unroll
    for (int g = 0; g < 16; ++g) {
        float a = 0.f;
#pragma unroll
        for (int j = 0; j < 8; ++j) {
            short8 kv = *(const short8*)(kb + g * 64 + j * 8);
#pragma unroll
            for (int i = 0; i < 8; ++i) a += qf[j * 8 + i] * b2f(kv[i]);
        }
        s[g] = a * 0.125f;
        mx = fmaxf(mx, s[g]);
    }
    float den = 0.f;
#pragma unroll
    for (int g = 0; g < 16; ++g) { s[g] = __expf(s[g] - mx); den += s[g]; }
    float inv = 1.f / den;

#pragma unroll
    for (int j = 0; j < 8; ++j) {
        float o[8] = {0.f, 0.f, 0.f, 0.f, 0.f, 0.f, 0.f, 0.f};
#pragma unroll
        for (int g = 0; g < 16; ++g) {
            short8 vv = *(const short8*)(vb + g * 64 + j * 8);
            float w = s[g];
#pragma unroll
            for (int i = 0; i < 8; ++i) o[i] += w * b2f(vv[i]);
        }
        short8 ov;
#pragma unroll
        for (int i = 0; i < 8; ++i) ov[i] = (short)f2b(o[i] * inv);
        *(short8*)(out + (size_t)t * 1024 + h * 64 + j * 8) = ov;
    }
}

// ---------- launch ----------
extern "C" void kernel_launch(void* const* d_in, const int* in_sizes, int n_in,
                              void* d_out, int out_size, void* d_ws, size_t ws_size,
                              hipStream_t stream) {
    const float* x  = (const float*)d_in[0];
    const float* Wq = (const float*)d_in[1];
    const float* bq = (const float*)d_in[2];
    const float* Wk = (const float*)d_in[3];
    const float* bk = (const float*)d_in[4];
    const float* Wv = (const float*)d_in[5];
    const float* bv = (const float*)d_in[6];
    const float* Wo = (const float*)d_in[7];
    const float* bo = (const float*)d_in[8];
    float* out = (float*)d_out;

    const int N = 32768, E = 1024;

    (void)hipFuncSetAttribute((const void*)gemm_dp<true>,  hipFuncAttributeMaxDynamicSharedMemorySize, 131072);
    (void)hipFuncSetAttribute((const void*)gemm_bt<false>, hipFuncAttributeMaxDynamicSharedMemorySize, 131072);

    char* ws = (char*)d_ws;
    size_t off = 0;
    short* xb = (short*)(ws + off);         off += (size_t)N * E * 2;
    short* wqkv = (short*)(ws + off);       off += (size_t)3 * E * E * 2;
    short* wo = (short*)(ws + off);         off += (size_t)E * E * 2;
    float* bqkv = (float*)(ws + off);       off += (size_t)3 * E * 4;
    off = (off + 255) & ~(size_t)255;
    short* y1 = (short*)(ws + off);         off += (size_t)N * 3 * E * 2;
    short* ao = xb;  // reuse xb: dead after GEMM1

    // 1) fused conversion
    cvt_all<<<dim3(18433), dim3(256), 0, stream>>>(
        x, Wq, Wk, Wv, Wo, bq, bk, bv,
        (unsigned short*)xb, (unsigned short*)wqkv, (unsigned short*)wo, bqkv);

    // 2) QKV projection (EXPERIMENTAL deep-pipeline 4-wave): grid 1536 (%8==0)
    gemm_dp<true><<<dim3((N / 256) * (3 * E / 256)), dim3(256), 131072, stream>>>(
        xb, wqkv, bqkv, (unsigned short*)y1, nullptr, N, 3 * E, E);

    // 3) per-token attention
    attn_k<<<dim3(N * 16 / 256), dim3(256), 0, stream>>>(y1, ao);

    // 4) output projection (R4-proven control): grid 512 (%8==0)
    gemm_bt<false><<<dim3((N / 256) * (E / 256)), dim3(512), 131072, stream>>>(
        ao, wo, bo, nullptr, out, N, E, E);
}

// Round 9
// 435.201 us; speedup vs baseline: 2.4505x; 2.4505x over previous
//
#include <hip/hip_runtime.h>

// ---------- types ----------
typedef __attribute__((ext_vector_type(8))) short short8;
typedef __attribute__((ext_vector_type(8))) unsigned short ushort8;
typedef __attribute__((ext_vector_type(4))) float f32x4;

__device__ __forceinline__ float b2f(short s) {
    unsigned u = ((unsigned)(unsigned short)s) << 16;
    return __builtin_bit_cast(float, u);
}
__device__ __forceinline__ unsigned short f2b(float f) {
    unsigned u = __builtin_bit_cast(unsigned, f);
    u += 0x7fffu + ((u >> 16) & 1u);   // round-to-nearest-even
    return (unsigned short)(u >> 16);
}

// global -> LDS async copy, 16B per lane (wave-uniform LDS base + lane*16)
__device__ __forceinline__ void gload_lds16(const void* gptr, void* ldsptr) {
    typedef __attribute__((address_space(1))) const void gv_t;
    typedef __attribute__((address_space(3))) void lv_t;
    gv_t* g = reinterpret_cast<gv_t*>(reinterpret_cast<unsigned long long>(gptr));
    lv_t* l = reinterpret_cast<lv_t*>((unsigned int)reinterpret_cast<unsigned long long>(ldsptr));
    __builtin_amdgcn_global_load_lds(g, l, 16, 0, 0);
}

#define MEMFENCE() asm volatile("" ::: "memory")
#define BARRIER() do { MEMFENCE(); __builtin_amdgcn_s_barrier(); MEMFENCE(); } while (0)

// ---------- one-shot fp32->bf16 conversion for all inputs + bias concat ----------
__global__ __launch_bounds__(256) void cvt_all(const float* __restrict__ x,
                                               const float* __restrict__ Wq,
                                               const float* __restrict__ Wk,
                                               const float* __restrict__ Wv,
                                               const float* __restrict__ Wo,
                                               const float* __restrict__ bq,
                                               const float* __restrict__ bk,
                                               const float* __restrict__ bv,
                                               unsigned short* __restrict__ xb,
                                               unsigned short* __restrict__ wqkv,
                                               unsigned short* __restrict__ wo,
                                               float* __restrict__ bqkv) {
    const int bid = blockIdx.x;
    const float* src;
    unsigned short* dst;
    int base8;
    if (bid < 16384)      { src = x;  dst = xb;              base8 = bid; }
    else if (bid < 16896) { src = Wq; dst = wqkv;            base8 = bid - 16384; }
    else if (bid < 17408) { src = Wk; dst = wqkv + 1048576;  base8 = bid - 16896; }
    else if (bid < 17920) { src = Wv; dst = wqkv + 2097152;  base8 = bid - 17408; }
    else if (bid < 18432) { src = Wo; dst = wo;              base8 = bid - 17920; }
    else {
        const int i = threadIdx.x;
#pragma unroll
        for (int r = 0; r < 12; ++r) {   // 3072 floats
            int j = r * 256 + i;
            float v = (j < 1024) ? bq[j] : (j < 2048 ? bk[j - 1024] : bv[j - 2048]);
            bqkv[j] = v;
        }
        return;
    }
    const size_t i8 = (size_t)base8 * 256 + threadIdx.x;
    const float4* p = (const float4*)src + i8 * 2;
    float4 a = p[0], b = p[1];
    ushort8 o;
    o[0] = f2b(a.x); o[1] = f2b(a.y); o[2] = f2b(a.z); o[3] = f2b(a.w);
    o[4] = f2b(b.x); o[5] = f2b(b.y); o[6] = f2b(b.z); o[7] = f2b(b.w);
    *(ushort8*)(dst + i8 * 8) = o;
}

// ---------- GEMM (R4-proven): 256x256, BK=64, 8 waves, 4-phase quadrant ----------
template <bool OUT_BF16>
__global__ __launch_bounds__(512, 2) void gemm_bt(const short* __restrict__ A,
                                                  const short* __restrict__ B,
                                                  const float* __restrict__ bias,
                                                  unsigned short* __restrict__ Cb,
                                                  float* __restrict__ Cf,
                                                  int M, int N, int K) {
    extern __shared__ short lds[];
    short* Ab = lds;                       // [2][2][128][64]
    short* Bb = lds + 2 * 2 * 128 * 64;    // [2][2][128][64]

    const int lane = threadIdx.x & 63;
    const int wave = threadIdx.x >> 6;
    const int wr = wave >> 2;
    const int wc = wave & 3;

    const int nwg = gridDim.x;
    const int bid = blockIdx.x;
    const int swz = (bid & 7) * (nwg >> 3) + (bid >> 3);
    const int ncol = N >> 8;
    const int trow = swz / ncol, tcol = swz % ncol;

    const short* Ablk = A + (size_t)trow * 256 * K;
    const short* Bblk = B + (size_t)tcol * 256 * K;

    const int scol_sw = ((lane & 7) ^ (lane >> 3)) * 8;
    const int rl = lane & 15;
    const int g0 = (((lane >> 4)) ^ (lane & 7)) * 8;
    const int g1 = ((4 + (lane >> 4)) ^ (lane & 7)) * 8;

    short8 af[4][2];
    short8 bf[4][2];
    f32x4 acc[8][4] = {};

    const int NT = K >> 6;
    const int smax = 4 * (NT - 2);

    auto stage_half = [&](int ts, int h) {
        const int dd = ts & 1;
        const int hh = h & 1;
        const short* gb = ((h < 2) ? Ablk : Bblk) + (size_t)(hh * 128) * K + (ts << 6) + scol_sw;
        short* lb = ((h < 2) ? Ab : Bb) + (((dd << 1) | hh) << 13);
#pragma unroll
        for (int c = 0; c < 2; ++c) {
            const int row = c * 64 + wave * 8 + (lane >> 3);
            gload_lds16(gb + (size_t)row * K, lb + ((c * 64 + wave * 8) << 6));
        }
    };
    auto stage_if = [&](int s) { if (s >= 0 && s < smax) stage_half((s >> 2) + 2, s & 3); };

    auto readA = [&](int d, int mh) {
        const short* base = Ab + (((d << 1) | wr) << 13) + ((mh * 64 + rl) << 6);
#pragma unroll
        for (int m = 0; m < 4; ++m) {
            af[m][0] = *(const short8*)(base + ((m * 16) << 6) + g0);
            af[m][1] = *(const short8*)(base + ((m * 16) << 6) + g1);
        }
    };
    auto readB = [&](int d, int nh) {
        const short* base = Bb + (((d << 1) | (wc >> 1)) << 13) + (((wc & 1) * 64 + rl) << 6);
#pragma unroll
        for (int j = 0; j < 2; ++j) {
            bf[nh * 2 + j][0] = *(const short8*)(base + (((nh * 2 + j) * 16) << 6) + g0);
            bf[nh * 2 + j][1] = *(const short8*)(base + (((nh * 2 + j) * 16) << 6) + g1);
        }
    };
    auto mm = [&](int mh, int nh) {
        __builtin_amdgcn_s_setprio(1);
#pragma unroll
        for (int ks = 0; ks < 2; ++ks)
#pragma unroll
            for (int m = 0; m < 4; ++m)
#pragma unroll
                for (int j = 0; j < 2; ++j)
                    acc[mh * 4 + m][nh * 2 + j] = __builtin_amdgcn_mfma_f32_16x16x32_bf16(
                        af[m][ks], bf[nh * 2 + j][ks], acc[mh * 4 + m][nh * 2 + j], 0, 0, 0);
        __builtin_amdgcn_s_setprio(0);
    };

    auto tile_body = [&](int T, int d) {
        const int s0 = 4 * T;
        readA(d, 0); readB(d, 0);
        stage_if(s0 - 3);
        asm volatile("s_waitcnt lgkmcnt(8)" ::: "memory");
        BARRIER();
        asm volatile("s_waitcnt lgkmcnt(0)" ::: "memory");
        mm(0, 0);
        BARRIER();
        readB(d, 1);
        stage_if(s0 - 2);
        BARRIER();
        asm volatile("s_waitcnt lgkmcnt(0)" ::: "memory");
        mm(0, 1);
        BARRIER();
        readA(d, 1);
        stage_if(s0 - 1);
        BARRIER();
        asm volatile("s_waitcnt lgkmcnt(0)" ::: "memory");
        mm(1, 0);
        BARRIER();
        stage_if(s0);
        BARRIER();
        mm(1, 1);
        if (T < NT - 2)       asm volatile("s_waitcnt vmcnt(2)" ::: "memory");
        else if (T == NT - 2) asm volatile("s_waitcnt vmcnt(0)" ::: "memory");
        BARRIER();
    };

#pragma unroll
    for (int t = 0; t < 2; ++t)
#pragma unroll
        for (int h = 0; h < 4; ++h) stage_half(t, h);
    asm volatile("s_waitcnt vmcnt(8)" ::: "memory");
    BARRIER();

    for (int T2 = 0; T2 < NT; T2 += 2) {
        tile_body(T2, 0);
        tile_body(T2 + 1, 1);
    }

    const int crow0 = trow * 256 + wr * 128 + (lane >> 4) * 4;
    const int ccol0 = tcol * 256 + wc * 64 + rl;
#pragma unroll
    for (int n = 0; n < 4; ++n) {
        const int col = ccol0 + n * 16;
        const float bv = bias[col];
#pragma unroll
        for (int m = 0; m < 8; ++m) {
            const int row0 = crow0 + m * 16;
#pragma unroll
            for (int r = 0; r < 4; ++r) {
                float val = acc[m][n][r] + bv;
                if (OUT_BF16) Cb[(size_t)(row0 + r) * N + col] = f2b(val);
                else          Cf[(size_t)(row0 + r) * N + col] = val;
            }
        }
    }
}

// ---------- per-token cross-head attention, LDS-staged K/V ----------
// block = 256 thr / 16 tokens. Stage K+V (16 x 2048 shorts = 64 KB) with
// coalesced 16B loads; per-token rotation (col + 8*token mod 2048) puts the
// wave's 4 tokens on disjoint bank groups (reads are 16-lane broadcasts ->
// conflict-free). Q from global (each thread's 8x16B fill one 128B line);
// output stores likewise L2-write-combine into full lines.
__global__ __launch_bounds__(256) void attn2(const short* __restrict__ qkv,
                                             short* __restrict__ out) {
    __shared__ short kv[16 * 2048];   // 64 KiB
    const int tid = threadIdx.x;
    const size_t t0 = (size_t)blockIdx.x * 16;

    // stage: r-th row's k+v (y1 cols 1024..3071), rotated by 8*r shorts
#pragma unroll
    for (int r = 0; r < 16; ++r) {
        short8 v = *(const short8*)(qkv + (t0 + r) * 3072 + 1024 + tid * 8);
        *(short8*)(kv + r * 2048 + ((tid * 8 + r * 8) & 2047)) = v;
    }
    __syncthreads();

    const int t = tid >> 4, h = tid & 15;
    const int rot = t * 8;
    const short* kt = kv + t * 2048;
    const short* q = qkv + (t0 + t) * 3072 + h * 64;

    float qf[64];
#pragma unroll
    for (int j = 0; j < 8; ++j) {
        short8 qv = *(const short8*)(q + j * 8);
#pragma unroll
        for (int i = 0; i < 8; ++i) qf[j * 8 + i] = b2f(qv[i]);
    }

    float s[16];
    float mx = -1e30f;
#pragma unroll
    for (int g = 0; g < 16; ++g) {
        float a = 0.f;
#pragma unroll
        for (int j = 0; j < 8; ++j) {
            short8 kvv = *(const short8*)(kt + ((g * 64 + j * 8 + rot) & 2047));
#pragma unroll
            for (int i = 0; i < 8; ++i) a += qf[j * 8 + i] * b2f(kvv[i]);
        }
        s[g] = a * 0.125f;   // scale = 1/sqrt(64)
        mx = fmaxf(mx, s[g]);
    }
    float den = 0.f;
#pragma unroll
    for (int g = 0; g < 16; ++g) { s[g] = __expf(s[g] - mx); den += s[g]; }
    float inv = 1.f / den;

#pragma unroll
    for (int j = 0; j < 8; ++j) {
        float o[8] = {0.f, 0.f, 0.f, 0.f, 0.f, 0.f, 0.f, 0.f};
#pragma unroll
        for (int g = 0; g < 16; ++g) {
            short8 vv = *(const short8*)(kt + ((1024 + g * 64 + j * 8 + rot) & 2047));
            float w = s[g];
#pragma unroll
            for (int i = 0; i < 8; ++i) o[i] += w * b2f(vv[i]);
        }
        short8 ov;
#pragma unroll
        for (int i = 0; i < 8; ++i) ov[i] = (short)f2b(o[i] * inv);
        *(short8*)(out + (t0 + t) * 1024 + h * 64 + j * 8) = ov;
    }
}

// ---------- launch ----------
extern "C" void kernel_launch(void* const* d_in, const int* in_sizes, int n_in,
                              void* d_out, int out_size, void* d_ws, size_t ws_size,
                              hipStream_t stream) {
    const float* x  = (const float*)d_in[0];
    const float* Wq = (const float*)d_in[1];
    const float* bq = (const float*)d_in[2];
    const float* Wk = (const float*)d_in[3];
    const float* bk = (const float*)d_in[4];
    const float* Wv = (const float*)d_in[5];
    const float* bv = (const float*)d_in[6];
    const float* Wo = (const float*)d_in[7];
    const float* bo = (const float*)d_in[8];
    float* out = (float*)d_out;

    const int N = 32768, E = 1024;
    const int LDS_BYTES = 131072;

    (void)hipFuncSetAttribute((const void*)gemm_bt<true>,  hipFuncAttributeMaxDynamicSharedMemorySize, LDS_BYTES);
    (void)hipFuncSetAttribute((const void*)gemm_bt<false>, hipFuncAttributeMaxDynamicSharedMemorySize, LDS_BYTES);

    char* ws = (char*)d_ws;
    size_t off = 0;
    short* xb = (short*)(ws + off);         off += (size_t)N * E * 2;
    short* wqkv = (short*)(ws + off);       off += (size_t)3 * E * E * 2;
    short* wo = (short*)(ws + off);         off += (size_t)E * E * 2;
    float* bqkv = (float*)(ws + off);       off += (size_t)3 * E * 4;
    off = (off + 255) & ~(size_t)255;
    short* y1 = (short*)(ws + off);         off += (size_t)N * 3 * E * 2;
    short* ao = xb;  // reuse xb: dead after GEMM1

    // 1) fused conversion (single launch)
    cvt_all<<<dim3(18433), dim3(256), 0, stream>>>(
        x, Wq, Wk, Wv, Wo, bq, bk, bv,
        (unsigned short*)xb, (unsigned short*)wqkv, (unsigned short*)wo, bqkv);

    // 2) QKV projection: grid 1536 (%8==0)
    gemm_bt<true><<<dim3((N / 256) * (3 * E / 256)), dim3(512), LDS_BYTES, stream>>>(
        xb, wqkv, bqkv, (unsigned short*)y1, nullptr, N, 3 * E, E);

    // 3) per-token attention, LDS-staged: 2048 blocks x 256 thr
    attn2<<<dim3(N / 16), dim3(256), 0, stream>>>(y1, ao);

    // 4) output projection: grid 512 (%8==0)
    gemm_bt<false><<<dim3((N / 256) * (E / 256)), dim3(512), LDS_BYTES, stream>>>(
        ao, wo, bo, nullptr, out, N, E, E);
}

// Round 10
// 425.584 us; speedup vs baseline: 2.5059x; 1.0226x over previous
//
#include <hip/hip_runtime.h>

// ---------- types ----------
typedef __attribute__((ext_vector_type(8))) short short8;
typedef __attribute__((ext_vector_type(8))) unsigned short ushort8;
typedef __attribute__((ext_vector_type(4))) float f32x4;

__device__ __forceinline__ float b2f(short s) {
    unsigned u = ((unsigned)(unsigned short)s) << 16;
    return __builtin_bit_cast(float, u);
}
__device__ __forceinline__ unsigned short f2b(float f) {
    unsigned u = __builtin_bit_cast(unsigned, f);
    u += 0x7fffu + ((u >> 16) & 1u);   // round-to-nearest-even
    return (unsigned short)(u >> 16);
}

// global -> LDS async copy, 16B per lane (wave-uniform LDS base + lane*16)
__device__ __forceinline__ void gload_lds16(const void* gptr, void* ldsptr) {
    typedef __attribute__((address_space(1))) const void gv_t;
    typedef __attribute__((address_space(3))) void lv_t;
    gv_t* g = reinterpret_cast<gv_t*>(reinterpret_cast<unsigned long long>(gptr));
    lv_t* l = reinterpret_cast<lv_t*>((unsigned int)reinterpret_cast<unsigned long long>(ldsptr));
    __builtin_amdgcn_global_load_lds(g, l, 16, 0, 0);
}

// ---------- one-shot fp32->bf16 conversion for all inputs + bias concat ----------
__global__ __launch_bounds__(256) void cvt_all(const float* __restrict__ x,
                                               const float* __restrict__ Wq,
                                               const float* __restrict__ Wk,
                                               const float* __restrict__ Wv,
                                               const float* __restrict__ Wo,
                                               const float* __restrict__ bq,
                                               const float* __restrict__ bk,
                                               const float* __restrict__ bv,
                                               unsigned short* __restrict__ xb,
                                               unsigned short* __restrict__ wqkv,
                                               unsigned short* __restrict__ wo,
                                               float* __restrict__ bqkv) {
    const int bid = blockIdx.x;
    const float* src;
    unsigned short* dst;
    int base8;
    if (bid < 16384)      { src = x;  dst = xb;              base8 = bid; }
    else if (bid < 16896) { src = Wq; dst = wqkv;            base8 = bid - 16384; }
    else if (bid < 17408) { src = Wk; dst = wqkv + 1048576;  base8 = bid - 16896; }
    else if (bid < 17920) { src = Wv; dst = wqkv + 2097152;  base8 = bid - 17408; }
    else if (bid < 18432) { src = Wo; dst = wo;              base8 = bid - 17920; }
    else {
        const int i = threadIdx.x;
#pragma unroll
        for (int r = 0; r < 12; ++r) {   // 3072 floats
            int j = r * 256 + i;
            float v = (j < 1024) ? bq[j] : (j < 2048 ? bk[j - 1024] : bv[j - 2048]);
            bqkv[j] = v;
        }
        return;
    }
    const size_t i8 = (size_t)base8 * 256 + threadIdx.x;
    const float4* p = (const float4*)src + i8 * 2;
    float4 a = p[0], b = p[1];
    ushort8 o;
    o[0] = f2b(a.x); o[1] = f2b(a.y); o[2] = f2b(a.z); o[3] = f2b(a.w);
    o[4] = f2b(b.x); o[5] = f2b(b.y); o[6] = f2b(b.z); o[7] = f2b(b.w);
    *(ushort8*)(dst + i8 * 8) = o;
}

// ---------- GEMM m97-style: 128x128 tile, BK=64, 4 waves, 32 KiB static LDS ----------
// Multi-block co-residency is the overlap mechanism (m97/m114): 3-5 blocks/CU;
// while one block drains gloads/ds_reads at its barrier, other blocks' waves
// feed the matrix pipe. Simple 2-barrier loop, single-buffered LDS.
// Granule-XOR swizzle (proven R4): stage source supplies logical granule
// (l&7)^(l>>3) so LDS phys granule p at row r holds logical p^ (r&7); reads
// use phys = g ^ (lane&7) (row&7 == lane&7 for all frag rows). Conflict-free.
// XCD-aware block swizzle (grid % 8 == 0). No setprio (m190: hurts this
// structure), no launch_bounds (let compiler pick VGPR; m97: ~164 -> 3 blk/CU).
template <bool OUT_BF16>
__global__ void gemm128(const short* __restrict__ A,   // [M,K] bf16
                        const short* __restrict__ B,   // [N,K] bf16
                        const float* __restrict__ bias,// [N]
                        unsigned short* __restrict__ Cb,
                        float* __restrict__ Cf,
                        int M, int N, int K) {
    __shared__ short As[128][64];
    __shared__ short Bs[128][64];

    const int lane = threadIdx.x & 63;
    const int wave = threadIdx.x >> 6;       // 0..3
    const int wr = wave >> 1, wc = wave & 1;

    const int nwg = gridDim.x;
    const int bid = blockIdx.x;
    const int swz = (bid & 7) * (nwg >> 3) + (bid >> 3);
    const int ncol = N >> 7;
    const int trow = swz / ncol, tcol = swz % ncol;

    // staging: lane l -> row wave*8 + (l>>3), phys granule l&7 (linear dest);
    // source column pre-swizzled: logical granule (l&7)^(l>>3)
    const int srow = wave * 8 + (lane >> 3);
    const int scol = ((lane & 7) ^ (lane >> 3)) * 8;
    const short* Abase = A + (size_t)(trow * 128 + srow) * K + scol;
    const short* Bbase = B + (size_t)(tcol * 128 + srow) * K + scol;
    short* AsBase = &As[wave * 8][0];
    short* BsBase = &Bs[wave * 8][0];

    const int rl = lane & 15;
    const int g0 = ((lane >> 4) ^ (lane & 7)) * 8;       // ks0 phys granule (shorts)
    const int g1 = ((4 + (lane >> 4)) ^ (lane & 7)) * 8; // ks1 phys granule

    f32x4 acc[4][4] = {};

    for (int kt = 0; kt < K; kt += 64) {
#pragma unroll
        for (int i = 0; i < 4; ++i) {
            gload_lds16(Abase + kt + (size_t)i * 32 * K, AsBase + i * 32 * 64);
            gload_lds16(Bbase + kt + (size_t)i * 32 * K, BsBase + i * 32 * 64);
        }
        __syncthreads();
#pragma unroll
        for (int ks = 0; ks < 2; ++ks) {
            const int g = ks ? g1 : g0;
            short8 af[4], bfr[4];
#pragma unroll
            for (int m = 0; m < 4; ++m)
                af[m] = *(const short8*)&As[wr * 64 + m * 16 + rl][g];
#pragma unroll
            for (int n = 0; n < 4; ++n)
                bfr[n] = *(const short8*)&Bs[wc * 64 + n * 16 + rl][g];
#pragma unroll
            for (int m = 0; m < 4; ++m)
#pragma unroll
                for (int n = 0; n < 4; ++n)
                    acc[m][n] = __builtin_amdgcn_mfma_f32_16x16x32_bf16(af[m], bfr[n], acc[m][n], 0, 0, 0);
        }
        __syncthreads();
    }

    // epilogue: C/D layout col = lane&15, row = (lane>>4)*4 + r
    const int crow0 = trow * 128 + wr * 64 + (lane >> 4) * 4;
    const int ccol0 = tcol * 128 + wc * 64 + rl;
#pragma unroll
    for (int n = 0; n < 4; ++n) {
        const int col = ccol0 + n * 16;
        const float bv = bias[col];
#pragma unroll
        for (int m = 0; m < 4; ++m) {
            const int row0 = crow0 + m * 16;
#pragma unroll
            for (int r = 0; r < 4; ++r) {
                float val = acc[m][n][r] + bv;
                if (OUT_BF16) Cb[(size_t)(row0 + r) * N + col] = f2b(val);
                else          Cf[(size_t)(row0 + r) * N + col] = val;
            }
        }
    }
}

// ---------- per-token cross-head attention, LDS-staged K/V (R9-proven) ----------
__global__ __launch_bounds__(256) void attn2(const short* __restrict__ qkv,
                                             short* __restrict__ out) {
    __shared__ short kv[16 * 2048];   // 64 KiB
    const int tid = threadIdx.x;
    const size_t t0 = (size_t)blockIdx.x * 16;

#pragma unroll
    for (int r = 0; r < 16; ++r) {
        short8 v = *(const short8*)(qkv + (t0 + r) * 3072 + 1024 + tid * 8);
        *(short8*)(kv + r * 2048 + ((tid * 8 + r * 8) & 2047)) = v;
    }
    __syncthreads();

    const int t = tid >> 4, h = tid & 15;
    const int rot = t * 8;
    const short* kt = kv + t * 2048;
    const short* q = qkv + (t0 + t) * 3072 + h * 64;

    float qf[64];
#pragma unroll
    for (int j = 0; j < 8; ++j) {
        short8 qv = *(const short8*)(q + j * 8);
#pragma unroll
        for (int i = 0; i < 8; ++i) qf[j * 8 + i] = b2f(qv[i]);
    }

    float s[16];
    float mx = -1e30f;
#pragma unroll
    for (int g = 0; g < 16; ++g) {
        float a = 0.f;
#pragma unroll
        for (int j = 0; j < 8; ++j) {
            short8 kvv = *(const short8*)(kt + ((g * 64 + j * 8 + rot) & 2047));
#pragma unroll
            for (int i = 0; i < 8; ++i) a += qf[j * 8 + i] * b2f(kvv[i]);
        }
        s[g] = a * 0.125f;
        mx = fmaxf(mx, s[g]);
    }
    float den = 0.f;
#pragma unroll
    for (int g = 0; g < 16; ++g) { s[g] = __expf(s[g] - mx); den += s[g]; }
    float inv = 1.f / den;

#pragma unroll
    for (int j = 0; j < 8; ++j) {
        float o[8] = {0.f, 0.f, 0.f, 0.f, 0.f, 0.f, 0.f, 0.f};
#pragma unroll
        for (int g = 0; g < 16; ++g) {
            short8 vv = *(const short8*)(kt + ((1024 + g * 64 + j * 8 + rot) & 2047));
            float w = s[g];
#pragma unroll
            for (int i = 0; i < 8; ++i) o[i] += w * b2f(vv[i]);
        }
        short8 ov;
#pragma unroll
        for (int i = 0; i < 8; ++i) ov[i] = (short)f2b(o[i] * inv);
        *(short8*)(out + (t0 + t) * 1024 + h * 64 + j * 8) = ov;
    }
}

// ---------- launch ----------
extern "C" void kernel_launch(void* const* d_in, const int* in_sizes, int n_in,
                              void* d_out, int out_size, void* d_ws, size_t ws_size,
                              hipStream_t stream) {
    const float* x  = (const float*)d_in[0];
    const float* Wq = (const float*)d_in[1];
    const float* bq = (const float*)d_in[2];
    const float* Wk = (const float*)d_in[3];
    const float* bk = (const float*)d_in[4];
    const float* Wv = (const float*)d_in[5];
    const float* bv = (const float*)d_in[6];
    const float* Wo = (const float*)d_in[7];
    const float* bo = (const float*)d_in[8];
    float* out = (float*)d_out;

    const int N = 32768, E = 1024;

    char* ws = (char*)d_ws;
    size_t off = 0;
    short* xb = (short*)(ws + off);         off += (size_t)N * E * 2;
    short* wqkv = (short*)(ws + off);       off += (size_t)3 * E * E * 2;
    short* wo = (short*)(ws + off);         off += (size_t)E * E * 2;
    float* bqkv = (float*)(ws + off);       off += (size_t)3 * E * 4;
    off = (off + 255) & ~(size_t)255;
    short* y1 = (short*)(ws + off);         off += (size_t)N * 3 * E * 2;
    short* ao = xb;  // reuse xb: dead after GEMM1

    // 1) fused conversion (single launch)
    cvt_all<<<dim3(18433), dim3(256), 0, stream>>>(
        x, Wq, Wk, Wv, Wo, bq, bk, bv,
        (unsigned short*)xb, (unsigned short*)wqkv, (unsigned short*)wo, bqkv);

    // 2) QKV projection: grid (32768/128)*(3072/128) = 256*24 = 6144 (%8==0)
    gemm128<true><<<dim3((N / 128) * (3 * E / 128)), dim3(256), 0, stream>>>(
        xb, wqkv, bqkv, (unsigned short*)y1, nullptr, N, 3 * E, E);

    // 3) per-token attention, LDS-staged: 2048 blocks x 256 thr
    attn2<<<dim3(N / 16), dim3(256), 0, stream>>>(y1, ao);

    // 4) output projection: grid 256*8 = 2048 (%8==0)
    gemm128<false><<<dim3((N / 128) * (E / 128)), dim3(256), 0, stream>>>(
        ao, wo, bo, nullptr, out, N, E, E);
}